// Round 1
// baseline (381.139 us; speedup 1.0000x reference)
//
#include <hip/hip_runtime.h>
#include <hip/hip_bf16.h>

// Dims (fixed by the problem)
#define BB 8
#define QQ 64
#define SS 64
#define TT 64
#define HH 8
#define DH 64
#define NHID 512
#define STAT_K 8
#define TOKEN_K 16

// ---------------------------------------------------------------------------
// Generic tiled fp32 GEMM  C[m,n] = sum_k A[m,k]*B[k,n]
// 32x32 tiles, 256 threads, 2x2 micro-tile. blockIdx.z applies element
// offsets az/bz/cz (used for per-head sub-matrix GEMMs).
// ---------------------------------------------------------------------------
__global__ __launch_bounds__(256) void gemm_nn(
    const float* __restrict__ A, const float* __restrict__ B, float* __restrict__ C,
    int M, int N, int K, int lda, int ldb, int ldc, int az, int bz, int cz)
{
    A += (long)blockIdx.z * az;
    B += (long)blockIdx.z * bz;
    C += (long)blockIdx.z * cz;
    __shared__ float As[32][33];
    __shared__ float Bs[32][33];
    const int tid = threadIdx.x;
    const int tx = tid & 15, ty = tid >> 4;
    const int row0 = blockIdx.y * 32, col0 = blockIdx.x * 32;
    float acc00 = 0.f, acc01 = 0.f, acc10 = 0.f, acc11 = 0.f;
    for (int k0 = 0; k0 < K; k0 += 32) {
        #pragma unroll
        for (int i = 0; i < 4; ++i) {
            int idx = tid + i * 256;
            int r = idx >> 5, k = idx & 31;
            As[r][k] = A[(row0 + r) * lda + k0 + k];
            Bs[r][k] = B[(k0 + r) * ldb + col0 + k];
        }
        __syncthreads();
        #pragma unroll
        for (int k = 0; k < 32; ++k) {
            float a0 = As[ty * 2][k], a1 = As[ty * 2 + 1][k];
            float b0 = Bs[k][tx * 2], b1 = Bs[k][tx * 2 + 1];
            acc00 += a0 * b0; acc01 += a0 * b1;
            acc10 += a1 * b0; acc11 += a1 * b1;
        }
        __syncthreads();
    }
    C[(row0 + ty * 2) * ldc + col0 + tx * 2]     = acc00;
    C[(row0 + ty * 2) * ldc + col0 + tx * 2 + 1] = acc01;
    C[(row0 + ty * 2 + 1) * ldc + col0 + tx * 2]     = acc10;
    C[(row0 + ty * 2 + 1) * ldc + col0 + tx * 2 + 1] = acc11;
}

// ---------------------------------------------------------------------------
// C[m,n] = sum_k A[m,k]*B[n,k]   (B transposed), same tiling.
// Used for qk_tok[r,h,e] = sum_d q_tok[r, h*64+d] * Wk_token[e, h*64+d]
// ---------------------------------------------------------------------------
__global__ __launch_bounds__(256) void gemm_abt(
    const float* __restrict__ A, const float* __restrict__ B, float* __restrict__ C,
    int M, int N, int K, int lda, int ldb, int ldc, int az, int bz, int cz)
{
    A += (long)blockIdx.z * az;
    B += (long)blockIdx.z * bz;
    C += (long)blockIdx.z * cz;
    __shared__ float As[32][33];
    __shared__ float Bs[32][33];
    const int tid = threadIdx.x;
    const int tx = tid & 15, ty = tid >> 4;
    const int row0 = blockIdx.y * 32, col0 = blockIdx.x * 32;
    float acc00 = 0.f, acc01 = 0.f, acc10 = 0.f, acc11 = 0.f;
    for (int k0 = 0; k0 < K; k0 += 32) {
        #pragma unroll
        for (int i = 0; i < 4; ++i) {
            int idx = tid + i * 256;
            int r = idx >> 5, k = idx & 31;
            As[r][k] = A[(row0 + r) * lda + k0 + k];   // coalesced over k
            Bs[r][k] = B[(col0 + r) * ldb + k0 + k];   // Bs[c][k], coalesced over k
        }
        __syncthreads();
        #pragma unroll
        for (int k = 0; k < 32; ++k) {
            float a0 = As[ty * 2][k], a1 = As[ty * 2 + 1][k];
            float b0 = Bs[tx * 2][k], b1 = Bs[tx * 2 + 1][k];
            acc00 += a0 * b0; acc01 += a0 * b1;
            acc10 += a1 * b0; acc11 += a1 * b1;
        }
        __syncthreads();
    }
    C[(row0 + ty * 2) * ldc + col0 + tx * 2]     = acc00;
    C[(row0 + ty * 2) * ldc + col0 + tx * 2 + 1] = acc01;
    C[(row0 + ty * 2 + 1) * ldc + col0 + tx * 2]     = acc10;
    C[(row0 + ty * 2 + 1) * ldc + col0 + tx * 2 + 1] = acc11;
}

// ---------------------------------------------------------------------------
// Stat scores + valid-len mask + top-8 + softmax over kept set.
// One wave (64 lanes) per (b,h,q); lane = segment s.
// ---------------------------------------------------------------------------
__global__ __launch_bounds__(64) void stat_topk(
    const float* __restrict__ q_stat, const float* __restrict__ k_stat,
    const int* __restrict__ valid_lens,
    int* __restrict__ sel_idx, float* __restrict__ sel_w)
{
    const int bid = blockIdx.x;           // b*512 + h*64 + q
    const int b = bid >> 9;
    const int hq = bid & 511;
    const int h = hq >> 6;
    const int q = hq & 63;
    const int lane = threadIdx.x;         // segment index s

    __shared__ float sq[64];
    sq[lane] = q_stat[(b * QQ + q) * NHID + h * DH + lane];
    __syncthreads();

    const float4* kr = (const float4*)(k_stat + (b * SS + lane) * NHID + h * DH);
    const float4* sq4 = (const float4*)sq;
    float sc = 0.f;
    #pragma unroll
    for (int i = 0; i < 16; ++i) {
        float4 a = sq4[i], kk = kr[i];
        sc += a.x * kk.x + a.y * kk.y + a.z * kk.z + a.w * kk.w;
    }
    sc *= 0.125f;                          // 1/sqrt(64)
    if (lane >= valid_lens[b]) sc = -1e6f;

    float my = sc;
    float mv[STAT_K];
    int   mi[STAT_K];
    #pragma unroll
    for (int j = 0; j < STAT_K; ++j) {
        float v = my;
        int idx = lane;
        #pragma unroll
        for (int off = 32; off > 0; off >>= 1) {
            float ov = __shfl_down(v, off);
            int   oi = __shfl_down(idx, off);
            if (ov > v || (ov == v && oi < idx)) { v = ov; idx = oi; }
        }
        v = __shfl(v, 0);
        idx = __shfl(idx, 0);
        mv[j] = v; mi[j] = idx;
        if (lane == idx) my = -3e38f;
    }
    // softmax over the 8 kept scores (mv[0] is the max).
    float m0 = mv[0];
    float den = 0.f;
    float w[STAT_K];
    #pragma unroll
    for (int j = 0; j < STAT_K; ++j) { w[j] = __expf(mv[j] - m0); den += w[j]; }
    float inv = 1.f / den;
    if (lane < STAT_K) {
        sel_idx[bid * STAT_K + lane] = mi[lane];
        sel_w[bid * STAT_K + lane]   = w[lane] * inv;
    }
}

// ---------------------------------------------------------------------------
// Token scores (last 16 tokens only), softmax, weighted value accumulation
// into ctx[b,q,h,e] (e over the full 512 hidden dims — Wv applied later).
// One 256-thread block per (b,h,q).
// ---------------------------------------------------------------------------
__global__ __launch_bounds__(256) void token_attend(
    const float* __restrict__ qk_tok, const float* __restrict__ token_keys,
    const float* __restrict__ values, const int* __restrict__ sel_idx,
    const float* __restrict__ sel_w, float* __restrict__ ctx)
{
    const int bid = blockIdx.x;           // b*512 + h*64 + q
    const int b = bid >> 9;
    const int hq = bid & 511;
    const int h = hq >> 6;
    const int q = hq & 63;
    const int tid = threadIdx.x;

    __shared__ float4 sqk[NHID / 4];
    __shared__ float sc[TOKEN_K];
    __shared__ float scw[TOKEN_K];
    __shared__ int   ssel[STAT_K];
    __shared__ float ssw[STAT_K];

    const float* qkrow = qk_tok + ((long)(b * QQ + q) * HH + h) * NHID;
    if (tid < NHID / 4) sqk[tid] = ((const float4*)qkrow)[tid];
    if (tid < STAT_K) {
        ssel[tid] = sel_idx[bid * STAT_K + tid];
        ssw[tid]  = sel_w[bid * STAT_K + tid];
    }
    __syncthreads();

    const int tok  = tid >> 4;   // 0..15
    const int part = tid & 15;   // 0..15
    float acc0 = 0.f, acc1 = 0.f;

    for (int j = 0; j < STAT_K; ++j) {
        const int s = ssel[j];
        const float wseg = ssw[j];
        const long base = ((long)(b * SS + s) * TT + (TT - TOKEN_K)) * NHID;

        // --- 16 token scores: 16 lanes per token, 512-dim dot (float4) ---
        const float4* krow = (const float4*)(token_keys + base + tok * NHID);
        float p = 0.f;
        #pragma unroll
        for (int i = 0; i < 8; ++i) {
            float4 a  = sqk[part + 16 * i];
            float4 kk = krow[part + 16 * i];
            p += a.x * kk.x + a.y * kk.y + a.z * kk.z + a.w * kk.w;
        }
        #pragma unroll
        for (int off = 8; off > 0; off >>= 1) p += __shfl_down(p, off, 16);
        if (part == 0) sc[tok] = p * 0.125f;
        __syncthreads();

        // --- softmax over 16 tokens, fold in segment weight ---
        if (tid < TOKEN_K) {
            float m = sc[0];
            #pragma unroll
            for (int t = 1; t < TOKEN_K; ++t) m = fmaxf(m, sc[t]);
            float den = 0.f;
            #pragma unroll
            for (int t = 0; t < TOKEN_K; ++t) den += __expf(sc[t] - m);
            scw[tid] = wseg * __expf(sc[tid] - m) / den;
        }
        __syncthreads();

        // --- accumulate weighted values: thread handles e = tid, tid+256 ---
        const float* vbase = values + base;
        #pragma unroll
        for (int t = 0; t < TOKEN_K; ++t) {
            float c = scw[t];
            acc0 += c * vbase[t * NHID + tid];
            acc1 += c * vbase[t * NHID + tid + 256];
        }
        __syncthreads();   // protect sc/scw before next segment
    }

    float* crow = ctx + ((long)(b * QQ + q) * HH + h) * NHID;
    crow[tid]       = acc0;
    crow[tid + 256] = acc1;
}

extern "C" void kernel_launch(void* const* d_in, const int* in_sizes, int n_in,
                              void* d_out, int out_size, void* d_ws, size_t ws_size,
                              hipStream_t stream) {
    const float* queries    = (const float*)d_in[0];   // [B,Q,NH]
    const float* stat_keys  = (const float*)d_in[1];   // [B,S,NH]
    const float* token_keys = (const float*)d_in[2];   // [B*S,T,NH]
    const float* values     = (const float*)d_in[3];   // [B*S,T,NH]
    const int*   valid_lens = (const int*)d_in[4];     // [B]
    const float* Wq_stat    = (const float*)d_in[5];
    const float* Wq_token   = (const float*)d_in[6];
    const float* Wk_stat    = (const float*)d_in[7];
    const float* Wk_token   = (const float*)d_in[8];
    const float* Wv         = (const float*)d_in[9];
    const float* Wo         = (const float*)d_in[10];
    float* out = (float*)d_out;

    float* ws = (float*)d_ws;
    float* q_stat  = ws;                    // 512*512
    float* t_tok   = ws + 262144;           // 512*512  (queries @ Wq_token)
    float* k_stat  = ws + 524288;           // 512*512
    float* qk_tok  = ws + 786432;           // 512*8*512 = 2M
    float* ctx     = ws + 2883584;          // 512*8*512 = 2M
    float* outv    = ws + 4980736;          // 512*512
    float* sel_w   = ws + 5242880;          // 4096*8
    int*   sel_idx = (int*)(ws + 5275648);  // 4096*8

    // --- projections (small GEMMs) ---
    gemm_nn<<<dim3(16, 16, 1), 256, 0, stream>>>(queries, Wq_stat, q_stat,
        512, 512, 512, 512, 512, 512, 0, 0, 0);
    gemm_nn<<<dim3(16, 16, 1), 256, 0, stream>>>(queries, Wq_token, t_tok,
        512, 512, 512, 512, 512, 512, 0, 0, 0);
    gemm_nn<<<dim3(16, 16, 1), 256, 0, stream>>>(stat_keys, Wk_stat, k_stat,
        512, 512, 512, 512, 512, 512, 0, 0, 0);
    // qk_tok[r,h,e] = sum_d t_tok[r, h*64+d] * Wk_token[e, h*64+d]
    gemm_abt<<<dim3(16, 16, 8), 256, 0, stream>>>(t_tok, Wk_token, qk_tok,
        512, 512, 64, 512, 512, 4096, 64, 64, 512);

    // --- stat attention: scores, mask, top-8, softmax ---
    stat_topk<<<dim3(4096), 64, 0, stream>>>(q_stat, k_stat, valid_lens,
        sel_idx, sel_w);

    // --- token attention over last 16 tokens of top-8 segments ---
    token_attend<<<dim3(4096), 256, 0, stream>>>(qk_tok, token_keys, values,
        sel_idx, sel_w, ctx);

    // --- outv[r, h*64+d] = sum_e ctx[r,h,e] * Wv[e, h*64+d]  (per head) ---
    gemm_nn<<<dim3(2, 16, 8), 256, 0, stream>>>(ctx, Wv, outv,
        512, 64, 512, 4096, 512, 512, 512, 64, 64);

    // --- final: out = outv @ Wo ---
    gemm_nn<<<dim3(16, 16, 1), 256, 0, stream>>>(outv, Wo, out,
        512, 512, 512, 512, 512, 512, 0, 0, 0);
}

// Round 2
// 269.989 us; speedup vs baseline: 1.4117x; 1.4117x over previous
//
#include <hip/hip_runtime.h>
#include <hip/hip_bf16.h>

#define BB 8
#define QQ 64
#define SS 64
#define TT 64
#define HH 8
#define DH 64
#define NHID 512
#define STAT_K 8
#define TOKEN_K 16

typedef short bf16x8 __attribute__((ext_vector_type(8)));
typedef float f32x4 __attribute__((ext_vector_type(4)));

__device__ inline ushort f2bf_rne(float x) {
    union { float f; unsigned u; } v; v.f = x;
    unsigned r = v.u + 0x7fff + ((v.u >> 16) & 1);
    return (ushort)(r >> 16);
}
__device__ inline float bf2f(ushort h) {
    union { unsigned u; float f; } v; v.u = ((unsigned)h) << 16;
    return v.f;
}

// ---------------------------------------------------------------------------
// Convert + transpose the six 512x512 weights into bf16 hi/lo planes:
// dst layout per z: hi[n][k] (262144 ush), lo[n][k] (262144 ush).
// ---------------------------------------------------------------------------
__global__ __launch_bounds__(256) void conv_wT(
    const float* w0, const float* w1, const float* w2,
    const float* w3, const float* w4, const float* w5, ushort* dst)
{
    const float* srcs[6] = {w0, w1, w2, w3, w4, w5};
    const float* src = srcs[blockIdx.z];
    ushort* hi = dst + (size_t)blockIdx.z * 524288;
    ushort* lo = hi + 262144;
    __shared__ float t[32][33];
    const int c0 = blockIdx.x * 32, r0 = blockIdx.y * 32;
    const int tx = threadIdx.x & 31, ty = threadIdx.x >> 5;  // ty 0..7
    #pragma unroll
    for (int i = 0; i < 4; ++i)
        t[ty + 8 * i][tx] = src[(r0 + ty + 8 * i) * 512 + c0 + tx];
    __syncthreads();
    #pragma unroll
    for (int i = 0; i < 4; ++i) {
        float x = t[tx][ty + 8 * i];
        ushort h = f2bf_rne(x);
        int o = (c0 + ty + 8 * i) * 512 + r0 + tx;
        hi[o] = h;
        lo[o] = f2bf_rne(x - bf2f(h));
    }
}

// Split a fp32 tensor into bf16 hi/lo planes (no transpose).
__global__ void conv_split(const float* __restrict__ src,
                           ushort* __restrict__ hi, ushort* __restrict__ lo, int n)
{
    int i = blockIdx.x * blockDim.x + threadIdx.x;
    if (i < n) {
        float x = src[i];
        ushort h = f2bf_rne(x);
        hi[i] = h;
        lo[i] = f2bf_rne(x - bf2f(h));
    }
}

// Extract last-16-token rows of a [512 segs, 64 tok, 512] tensor -> bf16 hi
// plane [8192, 512].
__global__ void conv_tok(const float* __restrict__ src, ushort* __restrict__ dst)
{
    int v = blockIdx.x * blockDim.x + threadIdx.x;   // over 8192*128 float4s
    int r = v >> 7, c = v & 127;
    int seg = r >> 4, tt = r & 15;
    const float4 x = *(const float4*)(src + (size_t)(seg * 64 + 48 + tt) * 512 + c * 4);
    ushort4 o;
    o.x = f2bf_rne(x.x); o.y = f2bf_rne(x.y);
    o.z = f2bf_rne(x.z); o.w = f2bf_rne(x.w);
    *(ushort4*)(dst + (size_t)v * 4) = o;
}

// ---------------------------------------------------------------------------
// MFMA bf16 GEMM: C[M,N] = A[M,K] @ B[K,N], with B given TRANSPOSED as
// Bt[N,K] bf16 planes. SPLIT: A,B have hi/lo planes, 3-term product
// (hi*hi + hi*lo + lo*hi) for ~fp32 accuracy. OUT_BF16: write C as bf16.
// 64x64 tile, BK=32, 256 threads = 4 waves of 32x32 (2x2 frags 16x16x32).
// M,N multiples of 64; K multiple of 32.
// ---------------------------------------------------------------------------
template <bool SPLIT, bool OUT_BF16>
__global__ __launch_bounds__(256) void gemm_mfma(
    const ushort* __restrict__ Ah, const ushort* __restrict__ Al,
    const ushort* __restrict__ Bh, const ushort* __restrict__ Bl,
    void* __restrict__ C, int M, int N, int K)
{
    __shared__ ushort As[SPLIT ? 2 : 1][64][40];   // +8 pad: 2-way banks (free)
    __shared__ ushort Bs[SPLIT ? 2 : 1][64][40];
    const int tid = threadIdx.x;
    const int row0 = blockIdx.y * 64, col0 = blockIdx.x * 64;
    const int wave = tid >> 6, lane = tid & 63;
    const int wm = wave & 1, wn = wave >> 1;
    const int m16 = lane & 15, quad = lane >> 4;
    const int srow = tid >> 2, schunk = tid & 3;

    f32x4 acc[2][2];
    #pragma unroll
    for (int i = 0; i < 2; ++i)
        #pragma unroll
        for (int j = 0; j < 2; ++j)
            #pragma unroll
            for (int r = 0; r < 4; ++r) acc[i][j][r] = 0.f;

    for (int k0 = 0; k0 < K; k0 += 32) {
        const size_t aoff = (size_t)(row0 + srow) * K + k0 + schunk * 8;
        const size_t boff = (size_t)(col0 + srow) * K + k0 + schunk * 8;
        uint4 a_h = *(const uint4*)(Ah + aoff);
        uint4 b_h = *(const uint4*)(Bh + boff);
        *(uint4*)&As[0][srow][schunk * 8] = a_h;
        *(uint4*)&Bs[0][srow][schunk * 8] = b_h;
        if constexpr (SPLIT) {
            uint4 a_l = *(const uint4*)(Al + aoff);
            uint4 b_l = *(const uint4*)(Bl + boff);
            *(uint4*)&As[1][srow][schunk * 8] = a_l;
            *(uint4*)&Bs[1][srow][schunk * 8] = b_l;
        }
        __syncthreads();

        bf16x8 af[2], bf[2], afl[2], bfl[2];
        #pragma unroll
        for (int i = 0; i < 2; ++i) {
            af[i] = *(const bf16x8*)&As[0][wm * 32 + i * 16 + m16][quad * 8];
            bf[i] = *(const bf16x8*)&Bs[0][wn * 32 + i * 16 + m16][quad * 8];
            if constexpr (SPLIT) {
                afl[i] = *(const bf16x8*)&As[1][wm * 32 + i * 16 + m16][quad * 8];
                bfl[i] = *(const bf16x8*)&Bs[1][wn * 32 + i * 16 + m16][quad * 8];
            }
        }
        #pragma unroll
        for (int i = 0; i < 2; ++i)
            #pragma unroll
            for (int j = 0; j < 2; ++j) {
                acc[i][j] = __builtin_amdgcn_mfma_f32_16x16x32_bf16(af[i], bf[j], acc[i][j], 0, 0, 0);
                if constexpr (SPLIT) {
                    acc[i][j] = __builtin_amdgcn_mfma_f32_16x16x32_bf16(af[i], bfl[j], acc[i][j], 0, 0, 0);
                    acc[i][j] = __builtin_amdgcn_mfma_f32_16x16x32_bf16(afl[i], bf[j], acc[i][j], 0, 0, 0);
                }
            }
        __syncthreads();
    }

    // C/D layout: col = lane&15, row = (lane>>4)*4 + reg   [m89/m91 verified]
    #pragma unroll
    for (int i = 0; i < 2; ++i)
        #pragma unroll
        for (int j = 0; j < 2; ++j) {
            int r0 = row0 + wm * 32 + i * 16 + quad * 4;
            int c = col0 + wn * 32 + j * 16 + m16;
            #pragma unroll
            for (int reg = 0; reg < 4; ++reg) {
                float v = acc[i][j][reg];
                if constexpr (OUT_BF16)
                    ((ushort*)C)[(size_t)(r0 + reg) * N + c] = f2bf_rne(v);
                else
                    ((float*)C)[(size_t)(r0 + reg) * N + c] = v;
            }
        }
}

// ---------------------------------------------------------------------------
// Stat scores + valid-len mask + top-8 + softmax (one wave per (b,h,q)).
// Needs fp32-accurate q_stat/k_stat (split GEMMs) so top-k matches reference.
// ---------------------------------------------------------------------------
__global__ __launch_bounds__(64) void stat_topk(
    const float* __restrict__ q_stat, const float* __restrict__ k_stat,
    const int* __restrict__ valid_lens,
    int* __restrict__ sel_idx, float* __restrict__ sel_w)
{
    const int bid = blockIdx.x;           // b*512 + h*64 + q
    const int b = bid >> 9;
    const int hq = bid & 511;
    const int h = hq >> 6;
    const int q = hq & 63;
    const int lane = threadIdx.x;         // segment index s

    __shared__ float sq[64];
    sq[lane] = q_stat[(b * QQ + q) * NHID + h * DH + lane];
    __syncthreads();

    const float4* kr = (const float4*)(k_stat + (b * SS + lane) * NHID + h * DH);
    const float4* sq4 = (const float4*)sq;
    float sc = 0.f;
    #pragma unroll
    for (int i = 0; i < 16; ++i) {
        float4 a = sq4[i], kk = kr[i];
        sc += a.x * kk.x + a.y * kk.y + a.z * kk.z + a.w * kk.w;
    }
    sc *= 0.125f;
    if (lane >= valid_lens[b]) sc = -1e6f;

    float my = sc;
    float mv[STAT_K];
    int   mi[STAT_K];
    #pragma unroll
    for (int j = 0; j < STAT_K; ++j) {
        float v = my;
        int idx = lane;
        #pragma unroll
        for (int off = 32; off > 0; off >>= 1) {
            float ov = __shfl_down(v, off);
            int   oi = __shfl_down(idx, off);
            if (ov > v || (ov == v && oi < idx)) { v = ov; idx = oi; }
        }
        v = __shfl(v, 0);
        idx = __shfl(idx, 0);
        mv[j] = v; mi[j] = idx;
        if (lane == idx) my = -3e38f;
    }
    float m0 = mv[0];
    float den = 0.f;
    float w[STAT_K];
    #pragma unroll
    for (int j = 0; j < STAT_K; ++j) { w[j] = __expf(mv[j] - m0); den += w[j]; }
    float inv = 1.f / den;
    if (lane < STAT_K) {
        sel_idx[bid * STAT_K + lane] = mi[lane];
        sel_w[bid * STAT_K + lane]   = w[lane] * inv;
    }
}

// ---------------------------------------------------------------------------
// Token attention over per-head projected keys/values (bf16, last-16 tokens).
// One wave per (b,h,q). Reads 8 segs x 16 tok x 64 dims x 2 tensors x 2B
// = 32 KB/block (was 512 KB in R1).
// ---------------------------------------------------------------------------
__global__ __launch_bounds__(64) void token_attend2(
    const float* __restrict__ q_tok, const ushort* __restrict__ k_tok,
    const ushort* __restrict__ v_proj, const int* __restrict__ sel_idx,
    const float* __restrict__ sel_w, float* __restrict__ ctx)
{
    const int bid = blockIdx.x;           // b*512 + h*64 + q
    const int b = bid >> 9, h = (bid >> 6) & 7, q = bid & 63;
    const int lane = threadIdx.x;

    __shared__ float sq[64];
    __shared__ float ssc[16];
    __shared__ int   ssel[STAT_K];
    __shared__ float ssw[STAT_K];

    sq[lane] = q_tok[(size_t)(b * QQ + q) * NHID + h * DH + lane];
    if (lane < STAT_K) {
        ssel[lane] = sel_idx[bid * STAT_K + lane];
        ssw[lane]  = sel_w[bid * STAT_K + lane];
    }
    __syncthreads();

    const int t = lane >> 2, part = lane & 3;   // 16 tokens x 4 lanes
    float acc = 0.f;

    for (int j = 0; j < STAT_K; ++j) {
        const int s = ssel[j];
        const float wseg = ssw[j];
        const size_t rowbase = (size_t)((b * SS + s) * TOKEN_K);

        // --- score: 4 lanes per token, 16 dims each ---
        const uint4* k4 = (const uint4*)(k_tok + (rowbase + t) * NHID + h * DH + part * 16);
        uint4 ka = k4[0], kb = k4[1];
        const float* qb = &sq[part * 16];
        float p = 0.f;
        p += qb[0]  * bf2f((ushort)(ka.x & 0xffff)) + qb[1]  * bf2f((ushort)(ka.x >> 16));
        p += qb[2]  * bf2f((ushort)(ka.y & 0xffff)) + qb[3]  * bf2f((ushort)(ka.y >> 16));
        p += qb[4]  * bf2f((ushort)(ka.z & 0xffff)) + qb[5]  * bf2f((ushort)(ka.z >> 16));
        p += qb[6]  * bf2f((ushort)(ka.w & 0xffff)) + qb[7]  * bf2f((ushort)(ka.w >> 16));
        p += qb[8]  * bf2f((ushort)(kb.x & 0xffff)) + qb[9]  * bf2f((ushort)(kb.x >> 16));
        p += qb[10] * bf2f((ushort)(kb.y & 0xffff)) + qb[11] * bf2f((ushort)(kb.y >> 16));
        p += qb[12] * bf2f((ushort)(kb.z & 0xffff)) + qb[13] * bf2f((ushort)(kb.z >> 16));
        p += qb[14] * bf2f((ushort)(kb.w & 0xffff)) + qb[15] * bf2f((ushort)(kb.w >> 16));
        p += __shfl_xor(p, 1);
        p += __shfl_xor(p, 2);
        if (part == 0) ssc[t] = p * 0.125f;
        __syncthreads();

        // --- softmax over 16 tokens (computed redundantly per lane) ---
        float m = ssc[0];
        #pragma unroll
        for (int tt = 1; tt < TOKEN_K; ++tt) m = fmaxf(m, ssc[tt]);
        float den = 0.f, wv[TOKEN_K];
        #pragma unroll
        for (int tt = 0; tt < TOKEN_K; ++tt) { wv[tt] = __expf(ssc[tt] - m); den += wv[tt]; }

        // --- weighted value accumulation: lane = dim d ---
        const ushort* vrow = v_proj + rowbase * NHID + h * DH + lane;
        float loc = 0.f;
        #pragma unroll
        for (int tt = 0; tt < TOKEN_K; ++tt) loc += wv[tt] * bf2f(vrow[tt * NHID]);
        acc += (wseg / den) * loc;
        __syncthreads();
    }

    ctx[(size_t)(b * QQ + q) * NHID + h * DH + lane] = acc;
}

extern "C" void kernel_launch(void* const* d_in, const int* in_sizes, int n_in,
                              void* d_out, int out_size, void* d_ws, size_t ws_size,
                              hipStream_t stream) {
    const float* queries    = (const float*)d_in[0];
    const float* stat_keys  = (const float*)d_in[1];
    const float* token_keys = (const float*)d_in[2];
    const float* values     = (const float*)d_in[3];
    const int*   valid_lens = (const int*)d_in[4];
    const float* Wq_stat    = (const float*)d_in[5];
    const float* Wq_token   = (const float*)d_in[6];
    const float* Wk_stat    = (const float*)d_in[7];
    const float* Wk_token   = (const float*)d_in[8];
    const float* Wv         = (const float*)d_in[9];
    const float* Wo         = (const float*)d_in[10];

    char* w = (char*)d_ws;                                  // ~39.1 MB total
    ushort* wT      = (ushort*)(w + 0);          // 6 x (hi+lo) x 262144 ush
    ushort* q_hi    = (ushort*)(w + 6291456);
    ushort* q_lo    = q_hi + 262144;
    ushort* sk_hi   = (ushort*)(w + 7340032);
    ushort* sk_lo   = sk_hi + 262144;
    float*  q_stat  = (float*)(w + 8388608);
    float*  k_stat  = (float*)(w + 9437184);
    float*  q_tokf  = (float*)(w + 10485760);
    ushort* tok_hi  = (ushort*)(w + 11534336);   // shared staging [8192,512]
    ushort* k_tok   = (ushort*)(w + 19922944);   // bf16 [8192,512]
    ushort* v_projp = (ushort*)(w + 28311552);   // bf16 [8192,512]
    float*  ctx     = (float*)(w + 36700160);
    ushort* ctx_hi  = (ushort*)(w + 37748736);
    ushort* ctx_lo  = ctx_hi + 262144;
    float*  sel_w   = (float*)(w + 38797312);
    int*    sel_idx = (int*)(w + 38928384);

    // weight plane pointers (z: 0=Wq_stat 1=Wk_stat 2=Wq_token 3=Wk_token 4=Wv 5=Wo)
    ushort* wqs_h = wT + 0 * 524288, *wqs_l = wqs_h + 262144;
    ushort* wks_h = wT + 1 * 524288, *wks_l = wks_h + 262144;
    ushort* wqt_h = wT + 2 * 524288, *wqt_l = wqt_h + 262144;
    ushort* wkt_h = wT + 3 * 524288;
    ushort* wv_h  = wT + 4 * 524288;
    ushort* wo_h  = wT + 5 * 524288, *wo_l = wo_h + 262144;

    // --- converts ---
    conv_wT<<<dim3(16, 16, 6), 256, 0, stream>>>(
        Wq_stat, Wk_stat, Wq_token, Wk_token, Wv, Wo, wT);
    conv_split<<<1024, 256, 0, stream>>>(queries, q_hi, q_lo, 262144);
    conv_split<<<1024, 256, 0, stream>>>(stat_keys, sk_hi, sk_lo, 262144);

    // --- stat path (split-bf16 = fp32-accurate for exact top-k) ---
    gemm_mfma<true, false><<<dim3(8, 8), 256, 0, stream>>>(
        q_hi, q_lo, wqs_h, wqs_l, q_stat, 512, 512, 512);
    gemm_mfma<true, false><<<dim3(8, 8), 256, 0, stream>>>(
        sk_hi, sk_lo, wks_h, wks_l, k_stat, 512, 512, 512);
    gemm_mfma<true, false><<<dim3(8, 8), 256, 0, stream>>>(
        q_hi, q_lo, wqt_h, wqt_l, q_tokf, 512, 512, 512);
    stat_topk<<<4096, 64, 0, stream>>>(q_stat, k_stat, valid_lens, sel_idx, sel_w);

    // --- token path: per-head projections of last-16 tokens (plain bf16) ---
    conv_tok<<<4096, 256, 0, stream>>>(token_keys, tok_hi);
    gemm_mfma<false, true><<<dim3(8, 128), 256, 0, stream>>>(
        tok_hi, nullptr, wkt_h, nullptr, k_tok, 8192, 512, 512);
    conv_tok<<<4096, 256, 0, stream>>>(values, tok_hi);
    gemm_mfma<false, true><<<dim3(8, 128), 256, 0, stream>>>(
        tok_hi, nullptr, wv_h, nullptr, v_projp, 8192, 512, 512);

    token_attend2<<<4096, 64, 0, stream>>>(q_tokf, k_tok, v_projp,
                                           sel_idx, sel_w, ctx);

    // --- output projection (split for margin; cheap at 512^3) ---
    conv_split<<<1024, 256, 0, stream>>>(ctx, ctx_hi, ctx_lo, 262144);
    gemm_mfma<true, false><<<dim3(8, 8), 256, 0, stream>>>(
        ctx_hi, ctx_lo, wo_h, wo_l, (float*)d_out, 512, 512, 512);
}

// Round 3
// 239.931 us; speedup vs baseline: 1.5885x; 1.1253x over previous
//
#include <hip/hip_runtime.h>
#include <hip/hip_bf16.h>

#define BB 8
#define QQ 64
#define SS 64
#define TT 64
#define HH 8
#define DH 64
#define NHID 512
#define STAT_K 8
#define TOKEN_K 16

typedef short bf16x8 __attribute__((ext_vector_type(8)));
typedef float f32x4 __attribute__((ext_vector_type(4)));

__device__ inline ushort f2bf_rne(float x) {
    union { float f; unsigned u; } v; v.f = x;
    unsigned r = v.u + 0x7fff + ((v.u >> 16) & 1);
    return (ushort)(r >> 16);
}
__device__ inline float bf2f(ushort h) {
    union { unsigned u; float f; } v; v.u = ((unsigned)h) << 16;
    return v.f;
}

// ---------------------------------------------------------------------------
// One fused convert pass. z<6: transpose+split weight z into bf16 hi/lo
// planes (layout hi[n][k], lo[n][k]). z==6: split queries. z==7: split
// stat_keys (no transpose).
// ---------------------------------------------------------------------------
__global__ __launch_bounds__(256) void conv_all(
    const float* w0, const float* w1, const float* w2,
    const float* w3, const float* w4, const float* w5,
    const float* queries, const float* stat_keys,
    ushort* wT, ushort* q_hi, ushort* q_lo, ushort* sk_hi, ushort* sk_lo)
{
    const int z = blockIdx.z;
    if (z < 6) {
        const float* srcs[6] = {w0, w1, w2, w3, w4, w5};
        const float* src = srcs[z];
        ushort* hi = wT + (size_t)z * 524288;
        ushort* lo = hi + 262144;
        __shared__ float t[32][33];
        const int c0 = blockIdx.x * 32, r0 = blockIdx.y * 32;
        const int tx = threadIdx.x & 31, ty = threadIdx.x >> 5;  // ty 0..7
        #pragma unroll
        for (int i = 0; i < 4; ++i)
            t[ty + 8 * i][tx] = src[(r0 + ty + 8 * i) * 512 + c0 + tx];
        __syncthreads();
        #pragma unroll
        for (int i = 0; i < 4; ++i) {
            float x = t[tx][ty + 8 * i];
            ushort h = f2bf_rne(x);
            int o = (c0 + ty + 8 * i) * 512 + r0 + tx;
            hi[o] = h;
            lo[o] = f2bf_rne(x - bf2f(h));
        }
    } else {
        const float* src = (z == 6) ? queries : stat_keys;
        ushort* hi = (z == 6) ? q_hi : sk_hi;
        ushort* lo = (z == 6) ? q_lo : sk_lo;
        int base = (blockIdx.y * 16 + blockIdx.x) * 1024 + threadIdx.x * 4;
        float4 x = *(const float4*)(src + base);
        ushort4 h, l;
        h.x = f2bf_rne(x.x); l.x = f2bf_rne(x.x - bf2f(h.x));
        h.y = f2bf_rne(x.y); l.y = f2bf_rne(x.y - bf2f(h.y));
        h.z = f2bf_rne(x.z); l.z = f2bf_rne(x.z - bf2f(h.z));
        h.w = f2bf_rne(x.w); l.w = f2bf_rne(x.w - bf2f(h.w));
        *(ushort4*)(hi + base) = h;
        *(ushort4*)(lo + base) = l;
    }
}

// ---------------------------------------------------------------------------
// z-batched split-bf16 MFMA GEMM (fp32-equivalent accuracy): 512x512x512.
// z=0: q @ Wq_stat -> q_stat ; z=1: sk @ Wk_stat -> k_stat ;
// z=2: q @ Wq_token -> q_tokf. B given transposed (Bt[N][K] planes).
// 64x64 tile, BK=32, 256 threads = 4 waves, 2x2 frags of 16x16x32.
// ---------------------------------------------------------------------------
__global__ __launch_bounds__(256) void gemm_split3(
    const ushort* __restrict__ q_hi, const ushort* __restrict__ q_lo,
    const ushort* __restrict__ sk_hi, const ushort* __restrict__ sk_lo,
    const ushort* __restrict__ wT,
    float* __restrict__ q_stat, float* __restrict__ k_stat,
    float* __restrict__ q_tokf)
{
    const int z = blockIdx.z;
    const ushort* Ah = (z == 1) ? sk_hi : q_hi;
    const ushort* Al = (z == 1) ? sk_lo : q_lo;
    // weight order in wT: 0=Wq_stat 1=Wk_stat 2=Wq_token
    const ushort* Bh = wT + (size_t)z * 524288;
    const ushort* Bl = Bh + 262144;
    float* C = (z == 0) ? q_stat : (z == 1) ? k_stat : q_tokf;
    const int K = 512, N = 512;

    __shared__ ushort As[2][64][40];
    __shared__ ushort Bs[2][64][40];
    const int tid = threadIdx.x;
    const int row0 = blockIdx.y * 64, col0 = blockIdx.x * 64;
    const int wave = tid >> 6, lane = tid & 63;
    const int wm = wave & 1, wn = wave >> 1;
    const int m16 = lane & 15, quad = lane >> 4;
    const int srow = tid >> 2, schunk = tid & 3;

    f32x4 acc[2][2];
    #pragma unroll
    for (int i = 0; i < 2; ++i)
        #pragma unroll
        for (int j = 0; j < 2; ++j)
            #pragma unroll
            for (int r = 0; r < 4; ++r) acc[i][j][r] = 0.f;

    for (int k0 = 0; k0 < K; k0 += 32) {
        const size_t aoff = (size_t)(row0 + srow) * K + k0 + schunk * 8;
        const size_t boff = (size_t)(col0 + srow) * K + k0 + schunk * 8;
        *(uint4*)&As[0][srow][schunk * 8] = *(const uint4*)(Ah + aoff);
        *(uint4*)&Bs[0][srow][schunk * 8] = *(const uint4*)(Bh + boff);
        *(uint4*)&As[1][srow][schunk * 8] = *(const uint4*)(Al + aoff);
        *(uint4*)&Bs[1][srow][schunk * 8] = *(const uint4*)(Bl + boff);
        __syncthreads();

        bf16x8 af[2], bf[2], afl[2], bfl[2];
        #pragma unroll
        for (int i = 0; i < 2; ++i) {
            af[i]  = *(const bf16x8*)&As[0][wm * 32 + i * 16 + m16][quad * 8];
            bf[i]  = *(const bf16x8*)&Bs[0][wn * 32 + i * 16 + m16][quad * 8];
            afl[i] = *(const bf16x8*)&As[1][wm * 32 + i * 16 + m16][quad * 8];
            bfl[i] = *(const bf16x8*)&Bs[1][wn * 32 + i * 16 + m16][quad * 8];
        }
        #pragma unroll
        for (int i = 0; i < 2; ++i)
            #pragma unroll
            for (int j = 0; j < 2; ++j) {
                acc[i][j] = __builtin_amdgcn_mfma_f32_16x16x32_bf16(af[i], bf[j], acc[i][j], 0, 0, 0);
                acc[i][j] = __builtin_amdgcn_mfma_f32_16x16x32_bf16(af[i], bfl[j], acc[i][j], 0, 0, 0);
                acc[i][j] = __builtin_amdgcn_mfma_f32_16x16x32_bf16(afl[i], bf[j], acc[i][j], 0, 0, 0);
            }
        __syncthreads();
    }

    #pragma unroll
    for (int i = 0; i < 2; ++i)
        #pragma unroll
        for (int j = 0; j < 2; ++j) {
            int r0 = row0 + wm * 32 + i * 16 + quad * 4;
            int c = col0 + wn * 32 + j * 16 + m16;
            #pragma unroll
            for (int reg = 0; reg < 4; ++reg)
                C[(size_t)(r0 + reg) * N + c] = acc[i][j][reg];
        }
}

// ---------------------------------------------------------------------------
// Final split GEMM: out = ctx(hi/lo) @ Wo(hi/lo), 512x512x512 -> fp32.
// ---------------------------------------------------------------------------
__global__ __launch_bounds__(256) void gemm_out(
    const ushort* __restrict__ Ah, const ushort* __restrict__ Al,
    const ushort* __restrict__ Bh, const ushort* __restrict__ Bl,
    float* __restrict__ C)
{
    const int K = 512, N = 512;
    __shared__ ushort As[2][64][40];
    __shared__ ushort Bs[2][64][40];
    const int tid = threadIdx.x;
    const int row0 = blockIdx.y * 64, col0 = blockIdx.x * 64;
    const int wave = tid >> 6, lane = tid & 63;
    const int wm = wave & 1, wn = wave >> 1;
    const int m16 = lane & 15, quad = lane >> 4;
    const int srow = tid >> 2, schunk = tid & 3;

    f32x4 acc[2][2];
    #pragma unroll
    for (int i = 0; i < 2; ++i)
        #pragma unroll
        for (int j = 0; j < 2; ++j)
            #pragma unroll
            for (int r = 0; r < 4; ++r) acc[i][j][r] = 0.f;

    for (int k0 = 0; k0 < K; k0 += 32) {
        const size_t aoff = (size_t)(row0 + srow) * K + k0 + schunk * 8;
        const size_t boff = (size_t)(col0 + srow) * K + k0 + schunk * 8;
        *(uint4*)&As[0][srow][schunk * 8] = *(const uint4*)(Ah + aoff);
        *(uint4*)&Bs[0][srow][schunk * 8] = *(const uint4*)(Bh + boff);
        *(uint4*)&As[1][srow][schunk * 8] = *(const uint4*)(Al + aoff);
        *(uint4*)&Bs[1][srow][schunk * 8] = *(const uint4*)(Bl + boff);
        __syncthreads();

        bf16x8 af[2], bf[2], afl[2], bfl[2];
        #pragma unroll
        for (int i = 0; i < 2; ++i) {
            af[i]  = *(const bf16x8*)&As[0][wm * 32 + i * 16 + m16][quad * 8];
            bf[i]  = *(const bf16x8*)&Bs[0][wn * 32 + i * 16 + m16][quad * 8];
            afl[i] = *(const bf16x8*)&As[1][wm * 32 + i * 16 + m16][quad * 8];
            bfl[i] = *(const bf16x8*)&Bs[1][wn * 32 + i * 16 + m16][quad * 8];
        }
        #pragma unroll
        for (int i = 0; i < 2; ++i)
            #pragma unroll
            for (int j = 0; j < 2; ++j) {
                acc[i][j] = __builtin_amdgcn_mfma_f32_16x16x32_bf16(af[i], bf[j], acc[i][j], 0, 0, 0);
                acc[i][j] = __builtin_amdgcn_mfma_f32_16x16x32_bf16(af[i], bfl[j], acc[i][j], 0, 0, 0);
                acc[i][j] = __builtin_amdgcn_mfma_f32_16x16x32_bf16(afl[i], bf[j], acc[i][j], 0, 0, 0);
            }
        __syncthreads();
    }

    #pragma unroll
    for (int i = 0; i < 2; ++i)
        #pragma unroll
        for (int j = 0; j < 2; ++j) {
            int r0 = row0 + wm * 32 + i * 16 + quad * 4;
            int c = col0 + wn * 32 + j * 16 + m16;
            #pragma unroll
            for (int reg = 0; reg < 4; ++reg)
                C[(size_t)(r0 + reg) * N + c] = acc[i][j][reg];
        }
}

// ---------------------------------------------------------------------------
// Token projections with fused fp32->bf16 conversion in the staging loads.
// A rows are the last-16-token slices of the raw [512,64,512] tensor:
// GEMM row r -> global row (r>>4)*64 + 48 + (r&15).
// z=0: token_keys @ Wk_token -> k_tok ; z=1: values @ Wv -> v_proj.
// Output bf16 [8192,512]. Plain bf16 (token path is softmax-smooth).
// ---------------------------------------------------------------------------
__global__ __launch_bounds__(256) void gemm_tok(
    const float* __restrict__ token_keys, const float* __restrict__ values,
    const ushort* __restrict__ wkt_h, const ushort* __restrict__ wv_h,
    ushort* __restrict__ k_tok, ushort* __restrict__ v_proj)
{
    const int z = blockIdx.z;
    const float* A = z ? values : token_keys;
    const ushort* Bh = z ? wv_h : wkt_h;
    ushort* C = z ? v_proj : k_tok;
    const int K = 512, N = 512;

    __shared__ ushort As[64][40];
    __shared__ ushort Bs[64][40];
    const int tid = threadIdx.x;
    const int row0 = blockIdx.y * 64, col0 = blockIdx.x * 64;
    const int wave = tid >> 6, lane = tid & 63;
    const int wm = wave & 1, wn = wave >> 1;
    const int m16 = lane & 15, quad = lane >> 4;
    const int srow = tid >> 2, schunk = tid & 3;

    const int r = row0 + srow;
    const size_t arow = (size_t)((r >> 4) * 64 + 48 + (r & 15)) * K;

    f32x4 acc[2][2];
    #pragma unroll
    for (int i = 0; i < 2; ++i)
        #pragma unroll
        for (int j = 0; j < 2; ++j)
            #pragma unroll
            for (int rr = 0; rr < 4; ++rr) acc[i][j][rr] = 0.f;

    for (int k0 = 0; k0 < K; k0 += 32) {
        const float* ap = A + arow + k0 + schunk * 8;
        float4 x0 = ((const float4*)ap)[0];
        float4 x1 = ((const float4*)ap)[1];
        ushort4 h0, h1;
        h0.x = f2bf_rne(x0.x); h0.y = f2bf_rne(x0.y);
        h0.z = f2bf_rne(x0.z); h0.w = f2bf_rne(x0.w);
        h1.x = f2bf_rne(x1.x); h1.y = f2bf_rne(x1.y);
        h1.z = f2bf_rne(x1.z); h1.w = f2bf_rne(x1.w);
        *(ushort4*)&As[srow][schunk * 8] = h0;
        *(ushort4*)&As[srow][schunk * 8 + 4] = h1;
        *(uint4*)&Bs[srow][schunk * 8] =
            *(const uint4*)(Bh + (size_t)(col0 + srow) * K + k0 + schunk * 8);
        __syncthreads();

        bf16x8 af[2], bf[2];
        #pragma unroll
        for (int i = 0; i < 2; ++i) {
            af[i] = *(const bf16x8*)&As[wm * 32 + i * 16 + m16][quad * 8];
            bf[i] = *(const bf16x8*)&Bs[wn * 32 + i * 16 + m16][quad * 8];
        }
        #pragma unroll
        for (int i = 0; i < 2; ++i)
            #pragma unroll
            for (int j = 0; j < 2; ++j)
                acc[i][j] = __builtin_amdgcn_mfma_f32_16x16x32_bf16(af[i], bf[j], acc[i][j], 0, 0, 0);
        __syncthreads();
    }

    #pragma unroll
    for (int i = 0; i < 2; ++i)
        #pragma unroll
        for (int j = 0; j < 2; ++j) {
            int r0 = row0 + wm * 32 + i * 16 + quad * 4;
            int c = col0 + wn * 32 + j * 16 + m16;
            #pragma unroll
            for (int reg = 0; reg < 4; ++reg)
                C[(size_t)(r0 + reg) * N + c] = f2bf_rne(acc[i][j][reg]);
        }
}

// ---------------------------------------------------------------------------
// Stat scores + valid-len mask + top-8 + softmax (one wave per (b,h,q)).
// ---------------------------------------------------------------------------
__global__ __launch_bounds__(64) void stat_topk(
    const float* __restrict__ q_stat, const float* __restrict__ k_stat,
    const int* __restrict__ valid_lens,
    int* __restrict__ sel_idx, float* __restrict__ sel_w)
{
    const int bid = blockIdx.x;           // b*512 + h*64 + q
    const int b = bid >> 9;
    const int hq = bid & 511;
    const int h = hq >> 6;
    const int q = hq & 63;
    const int lane = threadIdx.x;         // segment index s

    __shared__ float sq[64];
    sq[lane] = q_stat[(b * QQ + q) * NHID + h * DH + lane];
    __syncthreads();

    const float4* kr = (const float4*)(k_stat + (b * SS + lane) * NHID + h * DH);
    const float4* sq4 = (const float4*)sq;
    float sc = 0.f;
    #pragma unroll
    for (int i = 0; i < 16; ++i) {
        float4 a = sq4[i], kk = kr[i];
        sc += a.x * kk.x + a.y * kk.y + a.z * kk.z + a.w * kk.w;
    }
    sc *= 0.125f;
    if (lane >= valid_lens[b]) sc = -1e6f;

    float my = sc;
    float mv[STAT_K];
    int   mi[STAT_K];
    #pragma unroll
    for (int j = 0; j < STAT_K; ++j) {
        float v = my;
        int idx = lane;
        #pragma unroll
        for (int off = 32; off > 0; off >>= 1) {
            float ov = __shfl_down(v, off);
            int   oi = __shfl_down(idx, off);
            if (ov > v || (ov == v && oi < idx)) { v = ov; idx = oi; }
        }
        v = __shfl(v, 0);
        idx = __shfl(idx, 0);
        mv[j] = v; mi[j] = idx;
        if (lane == idx) my = -3e38f;
    }
    float m0 = mv[0];
    float den = 0.f;
    float w[STAT_K];
    #pragma unroll
    for (int j = 0; j < STAT_K; ++j) { w[j] = __expf(mv[j] - m0); den += w[j]; }
    float inv = 1.f / den;
    if (lane < STAT_K) {
        sel_idx[bid * STAT_K + lane] = mi[lane];
        sel_w[bid * STAT_K + lane]   = w[lane] * inv;
    }
}

// ---------------------------------------------------------------------------
// Token attention over per-head projected keys/values (bf16, last-16 tokens).
// One wave per (b,h,q). Writes ctx directly as bf16 hi/lo planes.
// ---------------------------------------------------------------------------
__global__ __launch_bounds__(64) void token_attend2(
    const float* __restrict__ q_tok, const ushort* __restrict__ k_tok,
    const ushort* __restrict__ v_proj, const int* __restrict__ sel_idx,
    const float* __restrict__ sel_w,
    ushort* __restrict__ ctx_hi, ushort* __restrict__ ctx_lo)
{
    const int bid = blockIdx.x;           // b*512 + h*64 + q
    const int b = bid >> 9, h = (bid >> 6) & 7, q = bid & 63;
    const int lane = threadIdx.x;

    __shared__ float sq[64];
    __shared__ float ssc[16];
    __shared__ int   ssel[STAT_K];
    __shared__ float ssw[STAT_K];

    sq[lane] = q_tok[(size_t)(b * QQ + q) * NHID + h * DH + lane];
    if (lane < STAT_K) {
        ssel[lane] = sel_idx[bid * STAT_K + lane];
        ssw[lane]  = sel_w[bid * STAT_K + lane];
    }
    __syncthreads();

    const int t = lane >> 2, part = lane & 3;   // 16 tokens x 4 lanes
    float acc = 0.f;

    for (int j = 0; j < STAT_K; ++j) {
        const int s = ssel[j];
        const float wseg = ssw[j];
        const size_t rowbase = (size_t)((b * SS + s) * TOKEN_K);

        const uint4* k4 = (const uint4*)(k_tok + (rowbase + t) * NHID + h * DH + part * 16);
        uint4 ka = k4[0], kb = k4[1];
        const float* qb = &sq[part * 16];
        float p = 0.f;
        p += qb[0]  * bf2f((ushort)(ka.x & 0xffff)) + qb[1]  * bf2f((ushort)(ka.x >> 16));
        p += qb[2]  * bf2f((ushort)(ka.y & 0xffff)) + qb[3]  * bf2f((ushort)(ka.y >> 16));
        p += qb[4]  * bf2f((ushort)(ka.z & 0xffff)) + qb[5]  * bf2f((ushort)(ka.z >> 16));
        p += qb[6]  * bf2f((ushort)(ka.w & 0xffff)) + qb[7]  * bf2f((ushort)(ka.w >> 16));
        p += qb[8]  * bf2f((ushort)(kb.x & 0xffff)) + qb[9]  * bf2f((ushort)(kb.x >> 16));
        p += qb[10] * bf2f((ushort)(kb.y & 0xffff)) + qb[11] * bf2f((ushort)(kb.y >> 16));
        p += qb[12] * bf2f((ushort)(kb.z & 0xffff)) + qb[13] * bf2f((ushort)(kb.z >> 16));
        p += qb[14] * bf2f((ushort)(kb.w & 0xffff)) + qb[15] * bf2f((ushort)(kb.w >> 16));
        p += __shfl_xor(p, 1);
        p += __shfl_xor(p, 2);
        if (part == 0) ssc[t] = p * 0.125f;
        __syncthreads();

        float m = ssc[0];
        #pragma unroll
        for (int tt = 1; tt < TOKEN_K; ++tt) m = fmaxf(m, ssc[tt]);
        float den = 0.f, wv[TOKEN_K];
        #pragma unroll
        for (int tt = 0; tt < TOKEN_K; ++tt) { wv[tt] = __expf(ssc[tt] - m); den += wv[tt]; }

        const ushort* vrow = v_proj + rowbase * NHID + h * DH + lane;
        float loc = 0.f;
        #pragma unroll
        for (int tt = 0; tt < TOKEN_K; ++tt) loc += wv[tt] * bf2f(vrow[tt * NHID]);
        acc += (wseg / den) * loc;
        __syncthreads();
    }

    const size_t o = (size_t)(b * QQ + q) * NHID + h * DH + lane;
    ushort hh = f2bf_rne(acc);
    ctx_hi[o] = hh;
    ctx_lo[o] = f2bf_rne(acc - bf2f(hh));
}

extern "C" void kernel_launch(void* const* d_in, const int* in_sizes, int n_in,
                              void* d_out, int out_size, void* d_ws, size_t ws_size,
                              hipStream_t stream) {
    const float* queries    = (const float*)d_in[0];
    const float* stat_keys  = (const float*)d_in[1];
    const float* token_keys = (const float*)d_in[2];
    const float* values     = (const float*)d_in[3];
    const int*   valid_lens = (const int*)d_in[4];
    const float* Wq_stat    = (const float*)d_in[5];
    const float* Wq_token   = (const float*)d_in[6];
    const float* Wk_stat    = (const float*)d_in[7];
    const float* Wk_token   = (const float*)d_in[8];
    const float* Wv         = (const float*)d_in[9];
    const float* Wo         = (const float*)d_in[10];

    char* w = (char*)d_ws;
    ushort* wT      = (ushort*)(w + 0);          // 6 x (hi+lo) x 262144 ush
    ushort* q_hi    = (ushort*)(w + 6291456);
    ushort* q_lo    = q_hi + 262144;
    ushort* sk_hi   = (ushort*)(w + 7340032);
    ushort* sk_lo   = sk_hi + 262144;
    float*  q_stat  = (float*)(w + 8388608);
    float*  k_stat  = (float*)(w + 9437184);
    float*  q_tokf  = (float*)(w + 10485760);
    ushort* k_tok   = (ushort*)(w + 11534336);   // bf16 [8192,512]
    ushort* v_projp = (ushort*)(w + 19922944);   // bf16 [8192,512]
    ushort* ctx_hi  = (ushort*)(w + 28311552);
    ushort* ctx_lo  = ctx_hi + 262144;
    float*  sel_w   = (float*)(w + 29360128);
    int*    sel_idx = (int*)(w + 29491200);

    // weight order in wT: 0=Wq_stat 1=Wk_stat 2=Wq_token 3=Wk_token 4=Wv 5=Wo
    ushort* wkt_h = wT + 3 * 524288;
    ushort* wv_h  = wT + 4 * 524288;
    ushort* wo_h  = wT + 5 * 524288, *wo_l = wo_h + 262144;

    // 1. all converts (weights transpose+split, queries/stat_keys split)
    conv_all<<<dim3(16, 16, 8), 256, 0, stream>>>(
        Wq_stat, Wk_stat, Wq_token, Wk_token, Wv, Wo,
        queries, stat_keys, wT, q_hi, q_lo, sk_hi, sk_lo);

    // 2. three split-precision projections in one z-batched launch
    gemm_split3<<<dim3(8, 8, 3), 256, 0, stream>>>(
        q_hi, q_lo, sk_hi, sk_lo, wT, q_stat, k_stat, q_tokf);

    // 3. stat top-8 + softmax
    stat_topk<<<4096, 64, 0, stream>>>(q_stat, k_stat, valid_lens, sel_idx, sel_w);

    // 4. token-path projections (fused fp32->bf16 staging, z=2)
    gemm_tok<<<dim3(8, 128, 2), 256, 0, stream>>>(
        token_keys, values, wkt_h, wv_h, k_tok, v_projp);

    // 5. token attention -> ctx (hi/lo planes)
    token_attend2<<<4096, 64, 0, stream>>>(q_tokf, k_tok, v_projp,
                                           sel_idx, sel_w, ctx_hi, ctx_lo);

    // 6. output projection
    gemm_out<<<dim3(8, 8), 256, 0, stream>>>(
        ctx_hi, ctx_lo, wo_h, wo_l, (float*)d_out);
}

// Round 4
// 224.388 us; speedup vs baseline: 1.6986x; 1.0693x over previous
//
#include <hip/hip_runtime.h>
#include <hip/hip_bf16.h>

#define BB 8
#define QQ 64
#define SS 64
#define TT 64
#define HH 8
#define DH 64
#define NHID 512
#define STAT_K 8
#define TOKEN_K 16

typedef short bf16x8 __attribute__((ext_vector_type(8)));
typedef float f32x4 __attribute__((ext_vector_type(4)));

__device__ inline ushort f2bf_rne(float x) {
    union { float f; unsigned u; } v; v.f = x;
    unsigned r = v.u + 0x7fff + ((v.u >> 16) & 1);
    return (ushort)(r >> 16);
}
__device__ inline float bf2f(ushort h) {
    union { unsigned u; float f; } v; v.u = ((unsigned)h) << 16;
    return v.f;
}

// ---------------------------------------------------------------------------
// One fused convert pass. z<6: transpose+split weight z into bf16 hi/lo
// planes (layout hi[n][k], lo[n][k]). z==6: split queries. z==7: split
// stat_keys (no transpose).
// ---------------------------------------------------------------------------
__global__ __launch_bounds__(256) void conv_all(
    const float* w0, const float* w1, const float* w2,
    const float* w3, const float* w4, const float* w5,
    const float* queries, const float* stat_keys,
    ushort* wT, ushort* q_hi, ushort* q_lo, ushort* sk_hi, ushort* sk_lo)
{
    const int z = blockIdx.z;
    if (z < 6) {
        const float* srcs[6] = {w0, w1, w2, w3, w4, w5};
        const float* src = srcs[z];
        ushort* hi = wT + (size_t)z * 524288;
        ushort* lo = hi + 262144;
        __shared__ float t[32][33];
        const int c0 = blockIdx.x * 32, r0 = blockIdx.y * 32;
        const int tx = threadIdx.x & 31, ty = threadIdx.x >> 5;  // ty 0..7
        #pragma unroll
        for (int i = 0; i < 4; ++i)
            t[ty + 8 * i][tx] = src[(r0 + ty + 8 * i) * 512 + c0 + tx];
        __syncthreads();
        #pragma unroll
        for (int i = 0; i < 4; ++i) {
            float x = t[tx][ty + 8 * i];
            ushort h = f2bf_rne(x);
            int o = (c0 + ty + 8 * i) * 512 + r0 + tx;
            hi[o] = h;
            lo[o] = f2bf_rne(x - bf2f(h));
        }
    } else {
        const float* src = (z == 6) ? queries : stat_keys;
        ushort* hi = (z == 6) ? q_hi : sk_hi;
        ushort* lo = (z == 6) ? q_lo : sk_lo;
        int base = (blockIdx.y * 16 + blockIdx.x) * 1024 + threadIdx.x * 4;
        float4 x = *(const float4*)(src + base);
        ushort4 h, l;
        h.x = f2bf_rne(x.x); l.x = f2bf_rne(x.x - bf2f(h.x));
        h.y = f2bf_rne(x.y); l.y = f2bf_rne(x.y - bf2f(h.y));
        h.z = f2bf_rne(x.z); l.z = f2bf_rne(x.z - bf2f(h.z));
        h.w = f2bf_rne(x.w); l.w = f2bf_rne(x.w - bf2f(h.w));
        *(ushort4*)(hi + base) = h;
        *(ushort4*)(lo + base) = l;
    }
}

// ---------------------------------------------------------------------------
// z-batched split-bf16 MFMA GEMM (fp32-equivalent accuracy): 512x512x512.
// z=0: q @ Wq_stat -> q_stat ; z=1: sk @ Wk_stat -> k_stat ;
// z=2: q @ Wq_token -> q_tokf. B given transposed (Bt[N][K] planes).
// ---------------------------------------------------------------------------
__global__ __launch_bounds__(256) void gemm_split3(
    const ushort* __restrict__ q_hi, const ushort* __restrict__ q_lo,
    const ushort* __restrict__ sk_hi, const ushort* __restrict__ sk_lo,
    const ushort* __restrict__ wT,
    float* __restrict__ q_stat, float* __restrict__ k_stat,
    float* __restrict__ q_tokf)
{
    const int z = blockIdx.z;
    const ushort* Ah = (z == 1) ? sk_hi : q_hi;
    const ushort* Al = (z == 1) ? sk_lo : q_lo;
    const ushort* Bh = wT + (size_t)z * 524288;
    const ushort* Bl = Bh + 262144;
    float* C = (z == 0) ? q_stat : (z == 1) ? k_stat : q_tokf;
    const int K = 512, N = 512;

    __shared__ ushort As[2][64][40];
    __shared__ ushort Bs[2][64][40];
    const int tid = threadIdx.x;
    const int row0 = blockIdx.y * 64, col0 = blockIdx.x * 64;
    const int wave = tid >> 6, lane = tid & 63;
    const int wm = wave & 1, wn = wave >> 1;
    const int m16 = lane & 15, quad = lane >> 4;
    const int srow = tid >> 2, schunk = tid & 3;

    f32x4 acc[2][2];
    #pragma unroll
    for (int i = 0; i < 2; ++i)
        #pragma unroll
        for (int j = 0; j < 2; ++j)
            #pragma unroll
            for (int r = 0; r < 4; ++r) acc[i][j][r] = 0.f;

    for (int k0 = 0; k0 < K; k0 += 32) {
        const size_t aoff = (size_t)(row0 + srow) * K + k0 + schunk * 8;
        const size_t boff = (size_t)(col0 + srow) * K + k0 + schunk * 8;
        *(uint4*)&As[0][srow][schunk * 8] = *(const uint4*)(Ah + aoff);
        *(uint4*)&Bs[0][srow][schunk * 8] = *(const uint4*)(Bh + boff);
        *(uint4*)&As[1][srow][schunk * 8] = *(const uint4*)(Al + aoff);
        *(uint4*)&Bs[1][srow][schunk * 8] = *(const uint4*)(Bl + boff);
        __syncthreads();

        bf16x8 af[2], bf[2], afl[2], bfl[2];
        #pragma unroll
        for (int i = 0; i < 2; ++i) {
            af[i]  = *(const bf16x8*)&As[0][wm * 32 + i * 16 + m16][quad * 8];
            bf[i]  = *(const bf16x8*)&Bs[0][wn * 32 + i * 16 + m16][quad * 8];
            afl[i] = *(const bf16x8*)&As[1][wm * 32 + i * 16 + m16][quad * 8];
            bfl[i] = *(const bf16x8*)&Bs[1][wn * 32 + i * 16 + m16][quad * 8];
        }
        #pragma unroll
        for (int i = 0; i < 2; ++i)
            #pragma unroll
            for (int j = 0; j < 2; ++j) {
                acc[i][j] = __builtin_amdgcn_mfma_f32_16x16x32_bf16(af[i], bf[j], acc[i][j], 0, 0, 0);
                acc[i][j] = __builtin_amdgcn_mfma_f32_16x16x32_bf16(af[i], bfl[j], acc[i][j], 0, 0, 0);
                acc[i][j] = __builtin_amdgcn_mfma_f32_16x16x32_bf16(afl[i], bf[j], acc[i][j], 0, 0, 0);
            }
        __syncthreads();
    }

    #pragma unroll
    for (int i = 0; i < 2; ++i)
        #pragma unroll
        for (int j = 0; j < 2; ++j) {
            int r0 = row0 + wm * 32 + i * 16 + quad * 4;
            int c = col0 + wn * 32 + j * 16 + m16;
            #pragma unroll
            for (int reg = 0; reg < 4; ++reg)
                C[(size_t)(r0 + reg) * N + c] = acc[i][j][reg];
        }
}

// ---------------------------------------------------------------------------
// Final split GEMM: out = ctx(hi/lo) @ Wo(hi/lo), 512x512x512 -> fp32.
// ---------------------------------------------------------------------------
__global__ __launch_bounds__(256) void gemm_out(
    const ushort* __restrict__ Ah, const ushort* __restrict__ Al,
    const ushort* __restrict__ Bh, const ushort* __restrict__ Bl,
    float* __restrict__ C)
{
    const int K = 512, N = 512;
    __shared__ ushort As[2][64][40];
    __shared__ ushort Bs[2][64][40];
    const int tid = threadIdx.x;
    const int row0 = blockIdx.y * 64, col0 = blockIdx.x * 64;
    const int wave = tid >> 6, lane = tid & 63;
    const int wm = wave & 1, wn = wave >> 1;
    const int m16 = lane & 15, quad = lane >> 4;
    const int srow = tid >> 2, schunk = tid & 3;

    f32x4 acc[2][2];
    #pragma unroll
    for (int i = 0; i < 2; ++i)
        #pragma unroll
        for (int j = 0; j < 2; ++j)
            #pragma unroll
            for (int r = 0; r < 4; ++r) acc[i][j][r] = 0.f;

    for (int k0 = 0; k0 < K; k0 += 32) {
        const size_t aoff = (size_t)(row0 + srow) * K + k0 + schunk * 8;
        const size_t boff = (size_t)(col0 + srow) * K + k0 + schunk * 8;
        *(uint4*)&As[0][srow][schunk * 8] = *(const uint4*)(Ah + aoff);
        *(uint4*)&Bs[0][srow][schunk * 8] = *(const uint4*)(Bh + boff);
        *(uint4*)&As[1][srow][schunk * 8] = *(const uint4*)(Al + aoff);
        *(uint4*)&Bs[1][srow][schunk * 8] = *(const uint4*)(Bl + boff);
        __syncthreads();

        bf16x8 af[2], bf[2], afl[2], bfl[2];
        #pragma unroll
        for (int i = 0; i < 2; ++i) {
            af[i]  = *(const bf16x8*)&As[0][wm * 32 + i * 16 + m16][quad * 8];
            bf[i]  = *(const bf16x8*)&Bs[0][wn * 32 + i * 16 + m16][quad * 8];
            afl[i] = *(const bf16x8*)&As[1][wm * 32 + i * 16 + m16][quad * 8];
            bfl[i] = *(const bf16x8*)&Bs[1][wn * 32 + i * 16 + m16][quad * 8];
        }
        #pragma unroll
        for (int i = 0; i < 2; ++i)
            #pragma unroll
            for (int j = 0; j < 2; ++j) {
                acc[i][j] = __builtin_amdgcn_mfma_f32_16x16x32_bf16(af[i], bf[j], acc[i][j], 0, 0, 0);
                acc[i][j] = __builtin_amdgcn_mfma_f32_16x16x32_bf16(af[i], bfl[j], acc[i][j], 0, 0, 0);
                acc[i][j] = __builtin_amdgcn_mfma_f32_16x16x32_bf16(afl[i], bf[j], acc[i][j], 0, 0, 0);
            }
        __syncthreads();
    }

    #pragma unroll
    for (int i = 0; i < 2; ++i)
        #pragma unroll
        for (int j = 0; j < 2; ++j) {
            int r0 = row0 + wm * 32 + i * 16 + quad * 4;
            int c = col0 + wn * 32 + j * 16 + m16;
            #pragma unroll
            for (int reg = 0; reg < 4; ++reg)
                C[(size_t)(r0 + reg) * N + c] = acc[i][j][reg];
        }
}

// ---------------------------------------------------------------------------
// Token projections, v2: 64x256 block tile (4 waves side-by-side in N, each
// wave 64x64 = 4x4 frags). A re-read factor 2 (was 8). Fused fp32->bf16 in
// A staging. A rows map to last-16-token slices: GEMM row r -> global row
// (r>>4)*64 + 48 + (r&15).
// z=0: token_keys @ Wk_token -> k_tok ; z=1: values @ Wv -> v_proj.
// ---------------------------------------------------------------------------
__global__ __launch_bounds__(256) void gemm_tok(
    const float* __restrict__ token_keys, const float* __restrict__ values,
    const ushort* __restrict__ wkt_h, const ushort* __restrict__ wv_h,
    ushort* __restrict__ k_tok, ushort* __restrict__ v_proj)
{
    const int z = blockIdx.z;
    const float* A = z ? values : token_keys;
    const ushort* Bh = z ? wv_h : wkt_h;
    ushort* C = z ? v_proj : k_tok;
    const int K = 512, N = 512;

    __shared__ ushort As[64][40];
    __shared__ ushort Bs[256][40];
    const int tid = threadIdx.x;
    const int row0 = blockIdx.y * 64, col0 = blockIdx.x * 256;
    const int wave = tid >> 6, lane = tid & 63;
    const int m16 = lane & 15, quad = lane >> 4;
    const int srow = tid >> 2, schunk = tid & 3;   // A staging: 64 rows x 4 chunks

    // A global row for this thread's staging row
    const int r = row0 + srow;
    const size_t arow = (size_t)((r >> 4) * 64 + 48 + (r & 15)) * K;

    f32x4 acc[4][4];
    #pragma unroll
    for (int i = 0; i < 4; ++i)
        #pragma unroll
        for (int j = 0; j < 4; ++j)
            #pragma unroll
            for (int rr = 0; rr < 4; ++rr) acc[i][j][rr] = 0.f;

    for (int k0 = 0; k0 < K; k0 += 32) {
        // --- stage A: 64x32 fp32 -> bf16. thread: 2 float4 -> 1 ds_write_b128
        const float* ap = A + arow + k0 + schunk * 8;
        float4 x0 = ((const float4*)ap)[0];
        float4 x1 = ((const float4*)ap)[1];
        ushort4 h0, h1;
        h0.x = f2bf_rne(x0.x); h0.y = f2bf_rne(x0.y);
        h0.z = f2bf_rne(x0.z); h0.w = f2bf_rne(x0.w);
        h1.x = f2bf_rne(x1.x); h1.y = f2bf_rne(x1.y);
        h1.z = f2bf_rne(x1.z); h1.w = f2bf_rne(x1.w);
        *(ushort4*)&As[srow][schunk * 8] = h0;
        *(ushort4*)&As[srow][schunk * 8 + 4] = h1;
        // --- stage B: 256x32 bf16, 4 uint4/thread
        #pragma unroll
        for (int i = 0; i < 4; ++i) {
            int v = tid + i * 256;
            int brow = v >> 2, bchunk = v & 3;
            *(uint4*)&Bs[brow][bchunk * 8] =
                *(const uint4*)(Bh + (size_t)(col0 + brow) * K + k0 + bchunk * 8);
        }
        __syncthreads();

        bf16x8 af[4], bf[4];
        #pragma unroll
        for (int i = 0; i < 4; ++i) {
            af[i] = *(const bf16x8*)&As[i * 16 + m16][quad * 8];
            bf[i] = *(const bf16x8*)&Bs[wave * 64 + i * 16 + m16][quad * 8];
        }
        #pragma unroll
        for (int i = 0; i < 4; ++i)
            #pragma unroll
            for (int j = 0; j < 4; ++j)
                acc[i][j] = __builtin_amdgcn_mfma_f32_16x16x32_bf16(af[i], bf[j], acc[i][j], 0, 0, 0);
        __syncthreads();
    }

    #pragma unroll
    for (int i = 0; i < 4; ++i)
        #pragma unroll
        for (int j = 0; j < 4; ++j) {
            int r0 = row0 + i * 16 + quad * 4;
            int c = col0 + wave * 64 + j * 16 + m16;
            #pragma unroll
            for (int reg = 0; reg < 4; ++reg)
                C[(size_t)(r0 + reg) * N + c] = f2bf_rne(acc[i][j][reg]);
        }
}

// ---------------------------------------------------------------------------
// Stat scores + valid-len mask + top-8 + softmax (one wave per (b,h,q)).
// ---------------------------------------------------------------------------
__global__ __launch_bounds__(64) void stat_topk(
    const float* __restrict__ q_stat, const float* __restrict__ k_stat,
    const int* __restrict__ valid_lens,
    int* __restrict__ sel_idx, float* __restrict__ sel_w)
{
    const int bid = blockIdx.x;           // b*512 + h*64 + q
    const int b = bid >> 9;
    const int hq = bid & 511;
    const int h = hq >> 6;
    const int q = hq & 63;
    const int lane = threadIdx.x;         // segment index s

    __shared__ float sq[64];
    sq[lane] = q_stat[(b * QQ + q) * NHID + h * DH + lane];
    __syncthreads();

    const float4* kr = (const float4*)(k_stat + (b * SS + lane) * NHID + h * DH);
    const float4* sq4 = (const float4*)sq;
    float sc = 0.f;
    #pragma unroll
    for (int i = 0; i < 16; ++i) {
        float4 a = sq4[i], kk = kr[i];
        sc += a.x * kk.x + a.y * kk.y + a.z * kk.z + a.w * kk.w;
    }
    sc *= 0.125f;
    if (lane >= valid_lens[b]) sc = -1e6f;

    float my = sc;
    float mv[STAT_K];
    int   mi[STAT_K];
    #pragma unroll
    for (int j = 0; j < STAT_K; ++j) {
        float v = my;
        int idx = lane;
        #pragma unroll
        for (int off = 32; off > 0; off >>= 1) {
            float ov = __shfl_down(v, off);
            int   oi = __shfl_down(idx, off);
            if (ov > v || (ov == v && oi < idx)) { v = ov; idx = oi; }
        }
        v = __shfl(v, 0);
        idx = __shfl(idx, 0);
        mv[j] = v; mi[j] = idx;
        if (lane == idx) my = -3e38f;
    }
    float m0 = mv[0];
    float den = 0.f;
    float w[STAT_K];
    #pragma unroll
    for (int j = 0; j < STAT_K; ++j) { w[j] = __expf(mv[j] - m0); den += w[j]; }
    float inv = 1.f / den;
    if (lane < STAT_K) {
        sel_idx[bid * STAT_K + lane] = mi[lane];
        sel_w[bid * STAT_K + lane]   = w[lane] * inv;
    }
}

// ---------------------------------------------------------------------------
// Token attention over per-head projected keys/values (bf16, last-16 tokens).
// One wave per (b,h,q). Writes ctx directly as bf16 hi/lo planes.
// ---------------------------------------------------------------------------
__global__ __launch_bounds__(64) void token_attend2(
    const float* __restrict__ q_tok, const ushort* __restrict__ k_tok,
    const ushort* __restrict__ v_proj, const int* __restrict__ sel_idx,
    const float* __restrict__ sel_w,
    ushort* __restrict__ ctx_hi, ushort* __restrict__ ctx_lo)
{
    const int bid = blockIdx.x;           // b*512 + h*64 + q
    const int b = bid >> 9, h = (bid >> 6) & 7, q = bid & 63;
    const int lane = threadIdx.x;

    __shared__ float sq[64];
    __shared__ float ssc[16];
    __shared__ int   ssel[STAT_K];
    __shared__ float ssw[STAT_K];

    sq[lane] = q_tok[(size_t)(b * QQ + q) * NHID + h * DH + lane];
    if (lane < STAT_K) {
        ssel[lane] = sel_idx[bid * STAT_K + lane];
        ssw[lane]  = sel_w[bid * STAT_K + lane];
    }
    __syncthreads();

    const int t = lane >> 2, part = lane & 3;   // 16 tokens x 4 lanes
    float acc = 0.f;

    for (int j = 0; j < STAT_K; ++j) {
        const int s = ssel[j];
        const float wseg = ssw[j];
        const size_t rowbase = (size_t)((b * SS + s) * TOKEN_K);

        const uint4* k4 = (const uint4*)(k_tok + (rowbase + t) * NHID + h * DH + part * 16);
        uint4 ka = k4[0], kb = k4[1];
        const float* qb = &sq[part * 16];
        float p = 0.f;
        p += qb[0]  * bf2f((ushort)(ka.x & 0xffff)) + qb[1]  * bf2f((ushort)(ka.x >> 16));
        p += qb[2]  * bf2f((ushort)(ka.y & 0xffff)) + qb[3]  * bf2f((ushort)(ka.y >> 16));
        p += qb[4]  * bf2f((ushort)(ka.z & 0xffff)) + qb[5]  * bf2f((ushort)(ka.z >> 16));
        p += qb[6]  * bf2f((ushort)(ka.w & 0xffff)) + qb[7]  * bf2f((ushort)(ka.w >> 16));
        p += qb[8]  * bf2f((ushort)(kb.x & 0xffff)) + qb[9]  * bf2f((ushort)(kb.x >> 16));
        p += qb[10] * bf2f((ushort)(kb.y & 0xffff)) + qb[11] * bf2f((ushort)(kb.y >> 16));
        p += qb[12] * bf2f((ushort)(kb.z & 0xffff)) + qb[13] * bf2f((ushort)(kb.z >> 16));
        p += qb[14] * bf2f((ushort)(kb.w & 0xffff)) + qb[15] * bf2f((ushort)(kb.w >> 16));
        p += __shfl_xor(p, 1);
        p += __shfl_xor(p, 2);
        if (part == 0) ssc[t] = p * 0.125f;
        __syncthreads();

        float m = ssc[0];
        #pragma unroll
        for (int tt = 1; tt < TOKEN_K; ++tt) m = fmaxf(m, ssc[tt]);
        float den = 0.f, wv[TOKEN_K];
        #pragma unroll
        for (int tt = 0; tt < TOKEN_K; ++tt) { wv[tt] = __expf(ssc[tt] - m); den += wv[tt]; }

        const ushort* vrow = v_proj + rowbase * NHID + h * DH + lane;
        float loc = 0.f;
        #pragma unroll
        for (int tt = 0; tt < TOKEN_K; ++tt) loc += wv[tt] * bf2f(vrow[tt * NHID]);
        acc += (wseg / den) * loc;
        __syncthreads();
    }

    const size_t o = (size_t)(b * QQ + q) * NHID + h * DH + lane;
    ushort hh = f2bf_rne(acc);
    ctx_hi[o] = hh;
    ctx_lo[o] = f2bf_rne(acc - bf2f(hh));
}

extern "C" void kernel_launch(void* const* d_in, const int* in_sizes, int n_in,
                              void* d_out, int out_size, void* d_ws, size_t ws_size,
                              hipStream_t stream) {
    const float* queries    = (const float*)d_in[0];
    const float* stat_keys  = (const float*)d_in[1];
    const float* token_keys = (const float*)d_in[2];
    const float* values     = (const float*)d_in[3];
    const int*   valid_lens = (const int*)d_in[4];
    const float* Wq_stat    = (const float*)d_in[5];
    const float* Wq_token   = (const float*)d_in[6];
    const float* Wk_stat    = (const float*)d_in[7];
    const float* Wk_token   = (const float*)d_in[8];
    const float* Wv         = (const float*)d_in[9];
    const float* Wo         = (const float*)d_in[10];

    char* w = (char*)d_ws;
    ushort* wT      = (ushort*)(w + 0);          // 6 x (hi+lo) x 262144 ush
    ushort* q_hi    = (ushort*)(w + 6291456);
    ushort* q_lo    = q_hi + 262144;
    ushort* sk_hi   = (ushort*)(w + 7340032);
    ushort* sk_lo   = sk_hi + 262144;
    float*  q_stat  = (float*)(w + 8388608);
    float*  k_stat  = (float*)(w + 9437184);
    float*  q_tokf  = (float*)(w + 10485760);
    ushort* k_tok   = (ushort*)(w + 11534336);   // bf16 [8192,512]
    ushort* v_projp = (ushort*)(w + 19922944);   // bf16 [8192,512]
    ushort* ctx_hi  = (ushort*)(w + 28311552);
    ushort* ctx_lo  = ctx_hi + 262144;
    float*  sel_w   = (float*)(w + 29360128);
    int*    sel_idx = (int*)(w + 29491200);

    // weight order in wT: 0=Wq_stat 1=Wk_stat 2=Wq_token 3=Wk_token 4=Wv 5=Wo
    ushort* wkt_h = wT + 3 * 524288;
    ushort* wv_h  = wT + 4 * 524288;
    ushort* wo_h  = wT + 5 * 524288, *wo_l = wo_h + 262144;

    // 1. all converts (weights transpose+split, queries/stat_keys split)
    conv_all<<<dim3(16, 16, 8), 256, 0, stream>>>(
        Wq_stat, Wk_stat, Wq_token, Wk_token, Wv, Wo,
        queries, stat_keys, wT, q_hi, q_lo, sk_hi, sk_lo);

    // 2. three split-precision projections in one z-batched launch
    gemm_split3<<<dim3(8, 8, 3), 256, 0, stream>>>(
        q_hi, q_lo, sk_hi, sk_lo, wT, q_stat, k_stat, q_tokf);

    // 3. stat top-8 + softmax
    stat_topk<<<4096, 64, 0, stream>>>(q_stat, k_stat, valid_lens, sel_idx, sel_w);

    // 4. token-path projections: 64x256 tiles, A re-read 2x (was 8x)
    gemm_tok<<<dim3(2, 128, 2), 256, 0, stream>>>(
        token_keys, values, wkt_h, wv_h, k_tok, v_projp);

    // 5. token attention -> ctx (hi/lo planes)
    token_attend2<<<4096, 64, 0, stream>>>(q_tokf, k_tok, v_projp,
                                           sel_idx, sel_w, ctx_hi, ctx_lo);

    // 6. output projection
    gemm_out<<<dim3(8, 8), 256, 0, stream>>>(
        ctx_hi, ctx_lo, wo_h, wo_l, (float*)d_out);
}